// Round 4
// baseline (163909.863 us; speedup 1.0000x reference)
//
#include <hip/hip_runtime.h>

#define TT 4096
#define NB 6

typedef unsigned int uint;
typedef unsigned long long u64;

// ---- relaxed agent-scope atoms (sc1): correct across non-coherent XCD L2s.
__device__ __forceinline__ u64 ldp(const u64* p) {
  return __hip_atomic_load(p, __ATOMIC_RELAXED, __HIP_MEMORY_SCOPE_AGENT);
}
__device__ __forceinline__ void stp(u64* p, float v, uint s) {
  u64 x = ((u64)s << 32) | (u64)__float_as_uint(v);
  __hip_atomic_store(p, x, __ATOMIC_RELAXED, __HIP_MEMORY_SCOPE_AGENT);
}
__device__ __forceinline__ uint ldf(const uint* p) {
  return __hip_atomic_load(p, __ATOMIC_RELAXED, __HIP_MEMORY_SCOPE_AGENT);
}
__device__ __forceinline__ void stf(uint* p, uint v) {
  __hip_atomic_store(p, v, __ATOMIC_RELAXED, __HIP_MEMORY_SCOPE_AGENT);
}

__device__ __forceinline__ float sigm(float x) { return 1.f / (1.f + __expf(-x)); }
__device__ __forceinline__ float ftanh(float x) {
  x = fminf(fmaxf(x, -15.f), 15.f);
  const float e = __expf(-2.f * x);
  return (1.f - e) / (1.f + e);
}

// wave-local LDS fence: my wave's ds_writes complete before my ds_reads.
__device__ __forceinline__ void lds_wave_fence() {
  asm volatile("s_waitcnt lgkmcnt(0)" ::: "memory");
  __builtin_amdgcn_sched_barrier(0);
}

// poll 6 atoms in ONE parallel shot per iteration (no sentinel serialization,
// no sleep in the common path). Stamps only advance (ring depth 8, skew<=1),
// so a matched atom stays matched; retry re-reads all 6 (still 1 round trip).
__device__ __forceinline__ void poll6(const u64* rs, uint st, float out[6]) {
  int spins = 0;
  for (;;) {
    const u64 a0 = ldp(rs + 0), a1 = ldp(rs + 1), a2 = ldp(rs + 2);
    const u64 a3 = ldp(rs + 3), a4 = ldp(rs + 4), a5 = ldp(rs + 5);
    if (((uint)(a0 >> 32) == st) & ((uint)(a1 >> 32) == st) &
        ((uint)(a2 >> 32) == st) & ((uint)(a3 >> 32) == st) &
        ((uint)(a4 >> 32) == st) & ((uint)(a5 >> 32) == st)) {
      out[0] = __uint_as_float((uint)a0); out[1] = __uint_as_float((uint)a1);
      out[2] = __uint_as_float((uint)a2); out[3] = __uint_as_float((uint)a3);
      out[4] = __uint_as_float((uint)a4); out[5] = __uint_as_float((uint)a5);
      return;
    }
    if (++spins >= 64) { __builtin_amdgcn_s_sleep(1); spins = 0; }
  }
}
__device__ __forceinline__ void poll2(const u64* rs, uint st, float out[2]) {
  int spins = 0;
  for (;;) {
    const u64 a0 = ldp(rs + 0), a1 = ldp(rs + 1);
    if (((uint)(a0 >> 32) == st) & ((uint)(a1 >> 32) == st)) {
      out[0] = __uint_as_float((uint)a0); out[1] = __uint_as_float((uint)a1);
      return;
    }
    if (++spins >= 64) { __builtin_amdgcn_s_sleep(1); spins = 0; }
  }
}

// acc[b] += v[k*6+b] * w  (LDS reads are wave-uniform => broadcast, free)
__device__ __forceinline__ void fma6(const float* vp, float w, float acc[6]) {
  const float2 v0 = *(const float2*)(vp);
  const float2 v1 = *(const float2*)(vp + 2);
  const float2 v2 = *(const float2*)(vp + 4);
  acc[0] += v0.x * w; acc[1] += v0.y * w; acc[2] += v1.x * w;
  acc[3] += v1.y * w; acc[4] += v2.x * w; acc[5] += v2.y * w;
}

#define ZSTRIDE 520  // 64 cols * 8 + 8 pad: spreads gate-read banks across p

// ================= K1: LSTM layer 1 — 32 WGs x 512 thr, 16 units/WG =========
// col = tid&63 (4 gates x 16 units), wave w = tid>>6 = k-slice index.
// Thread tid polls unit tid (6 atoms); wave w FMAs h-k [64w,64w+64) — its own
// polled slice (no barrier between poll and FMA). One __syncthreads per step.
__global__ __launch_bounds__(512) void k_l1(
    const float* __restrict__ x, const float* __restrict__ Wi,
    const float* __restrict__ Wh, const float* __restrict__ bias,
    u64* h1ring, u64* h2ring, float* c1fin, float* seq1) {
  __shared__ float xl[2][128 * 6];
  __shared__ float hl[512 * 6];
  __shared__ float zred[8 * ZSTRIDE];
  __shared__ float bs[64];
  const int tid = threadIdx.x, wg = blockIdx.x;
  const int c = tid & 63, w = tid >> 6;
  const int u0 = wg * 16;
  const int gcol = ((c >> 4) * 512) + u0 + (c & 15);
  float wh[64], wx[16];
#pragma unroll
  for (int kk = 0; kk < 64; ++kk) wh[kk] = Wh[(size_t)(w * 64 + kk) * 2048 + gcol];
#pragma unroll
  for (int kk = 0; kk < 16; ++kk) wx[kk] = Wi[(size_t)(w * 16 + kk) * 2048 + gcol];
  if (tid < 64) bs[tid] = bias[((tid >> 4) * 512) + u0 + (tid & 15)];
  const int gj = tid / 6, gb = tid % 6;  // gate lanes: tid<96
  float creg = 0.f;
  // prologue: stage x[0] into xl[0] (transpose [b][k] -> [k][6])
  {
    const float v0 = x[tid];
    float v1 = 0.f;
    if (tid < 256) v1 = x[512 + tid];
    xl[0][(tid & 127) * 6 + (tid >> 7)] = v0;
    if (tid < 256) { const int i = 512 + tid; xl[0][(i & 127) * 6 + (i >> 7)] = v1; }
  }
  __syncthreads();

  for (int t = 0; t < TT; ++t) {
    // prefetch x[t+1] into regs (consumed at stage; latency hidden)
    const float* xn = x + (size_t)((t + 1 < TT) ? t + 1 : TT - 1) * 768;
    const float v0p = xn[tid];
    float v1p = 0.f;
    if (tid < 256) v1p = xn[512 + tid];
    // x-part (overlaps the poll)
    float acc[6] = {0, 0, 0, 0, 0, 0};
    {
      const float* xb = xl[t & 1] + (size_t)(w * 16) * 6;
#pragma unroll
      for (int kk = 0; kk < 16; ++kk) fma6(xb + kk * 6, wx[kk], acc);
    }
    // poll h[t-1] for unit tid
    {
      float hv[6];
      poll6(h1ring + (size_t)((t + 7) & 7) * 3072 + tid * 6, (uint)t, hv);
      float* hp = hl + tid * 6;
      *(float2*)(hp) = make_float2(hv[0], hv[1]);
      *(float2*)(hp + 2) = make_float2(hv[2], hv[3]);
      *(float2*)(hp + 4) = make_float2(hv[4], hv[5]);
    }
    lds_wave_fence();  // wave w wrote hl[64w..64w+64) == slice it reads below
    {
      const float* hb = hl + (size_t)(w * 64) * 6;
#pragma unroll
      for (int kk = 0; kk < 64; ++kk) fma6(hb + kk * 6, wh[kk], acc);
    }
    {
      float* zr = zred + w * ZSTRIDE + c * 8;
      *(float4*)zr = make_float4(acc[0], acc[1], acc[2], acc[3]);
      *(float2*)(zr + 4) = make_float2(acc[4], acc[5]);
    }
    // stage xl[(t+1)&1]
    {
      float* xs = xl[(t + 1) & 1];
      xs[(tid & 127) * 6 + (tid >> 7)] = v0p;
      if (tid < 256) { const int i = 512 + tid; xs[(i & 127) * 6 + (i >> 7)] = v1p; }
    }
    __syncthreads();  // B (the only barrier per step)
    if (tid < 96) {
      __builtin_amdgcn_s_setprio(1);
      float z[4];
#pragma unroll
      for (int g = 0; g < 4; ++g) {
        const int cc = g * 16 + gj;
        float s = 0.f;
#pragma unroll
        for (int p = 0; p < 8; ++p) s += zred[p * ZSTRIDE + cc * 8 + gb];
        z[g] = s + bs[cc];
      }
      creg = sigm(z[1]) * creg + sigm(z[0]) * ftanh(z[2]);
      const float hval = sigm(z[3]) * ftanh(creg);
      const int gu = u0 + gj;
      stp(h1ring + (size_t)(t & 7) * 3072 + gu * 6 + gb, hval, (uint)(t + 1));
      seq1[(size_t)t * 4096 + gu * 8 + gb] = hval;  // padded [t][512][8]
      if (t == TT - 1) {
        stp(h2ring + (size_t)7 * 3072 + gu * 6 + gb, hval, 0u);  // L2 h-init
        c1fin[gu * 6 + gb] = creg;
      }
      __builtin_amdgcn_s_setprio(0);
    }
  }
}

// ===== K2: L2 (WGs 0..31, 16 units) + L3 (WGs 32..39, 16 units), skewed =====
__global__ __launch_bounds__(512) void k_l23(
    const float* __restrict__ seq1, const float* __restrict__ Wi2,
    const float* __restrict__ Wh2, const float* __restrict__ b2,
    const float* __restrict__ Wi3, const float* __restrict__ Wh3,
    const float* __restrict__ b3, const float* __restrict__ c1fin,
    u64* h2ring, u64* h3ring, float* h3fin, uint* flags3) {
  __shared__ float smem[13440];
  const int tid = threadIdx.x, wg = blockIdx.x;
  const int c = tid & 63, w = tid >> 6;
  const int gj = tid / 6, gb = tid % 6;

  if (wg < 32) {
    // --------------- L2: x = seq1[t] (K=512), h2 (K=512) --------------------
    float* xls = smem;                    // 2 x 3072
    float* hl = smem + 6144;              // 3072
    float* zred = smem + 9216;            // 8*520 = 4160
    float* bsl = smem + 13376;            // 64
    const int u0 = wg * 16;
    const int gcol = ((c >> 4) * 512) + u0 + (c & 15);
    float wh[64], wx[64];
#pragma unroll
    for (int kk = 0; kk < 64; ++kk) {
      wh[kk] = Wh2[(size_t)(w * 64 + kk) * 2048 + gcol];
      wx[kk] = Wi2[(size_t)(w * 64 + kk) * 2048 + gcol];
    }
    if (tid < 64) bsl[tid] = b2[((tid >> 4) * 512) + u0 + (tid & 15)];
    float creg = (tid < 96) ? c1fin[(u0 + gj) * 6 + gb] : 0.f;
    // prologue: stage seq1[0] (wave-self slice: thread tid = k-row tid)
    {
      const float4 s0 = *(const float4*)(seq1 + (size_t)tid * 8);
      const float2 s1 = *(const float2*)(seq1 + (size_t)tid * 8 + 4);
      float* xs = xls + tid * 6;
      *(float2*)(xs) = make_float2(s0.x, s0.y);
      *(float2*)(xs + 2) = make_float2(s0.z, s0.w);
      *(float2*)(xs + 4) = make_float2(s1.x, s1.y);
    }
    __syncthreads();

    for (int t = 0; t < TT; ++t) {
      // WAR vs L3 (every 4 steps): one lane per flag; barrier B orders posts.
      if ((t & 3) == 0 && t >= 8 && tid < 8) {
        const uint need = (uint)(t - 4);
        while (ldf(flags3 + tid) < need) __builtin_amdgcn_s_sleep(1);
      }
      // prefetch seq1[t+1]
      const float* sn = seq1 + (size_t)((t + 1 < TT) ? t + 1 : TT - 1) * 4096;
      const float4 p0 = *(const float4*)(sn + (size_t)tid * 8);
      const float2 p1 = *(const float2*)(sn + (size_t)tid * 8 + 4);
      // x-part (overlaps the poll)
      float acc[6] = {0, 0, 0, 0, 0, 0};
      {
        const float* xb = xls + (size_t)(t & 1) * 3072 + (size_t)(w * 64) * 6;
#pragma unroll
        for (int kk = 0; kk < 64; ++kk) fma6(xb + kk * 6, wx[kk], acc);
      }
      // poll h2[t-1] for unit tid
      {
        float hv[6];
        poll6(h2ring + (size_t)((t + 7) & 7) * 3072 + tid * 6, (uint)t, hv);
        float* hp = hl + tid * 6;
        *(float2*)(hp) = make_float2(hv[0], hv[1]);
        *(float2*)(hp + 2) = make_float2(hv[2], hv[3]);
        *(float2*)(hp + 4) = make_float2(hv[4], hv[5]);
      }
      lds_wave_fence();
      {
        const float* hb = hl + (size_t)(w * 64) * 6;
#pragma unroll
        for (int kk = 0; kk < 64; ++kk) fma6(hb + kk * 6, wh[kk], acc);
      }
      {
        float* zr = zred + w * ZSTRIDE + c * 8;
        *(float4*)zr = make_float4(acc[0], acc[1], acc[2], acc[3]);
        *(float2*)(zr + 4) = make_float2(acc[4], acc[5]);
      }
      // stage xls[(t+1)&1] (wave-self slice)
      {
        float* xs = xls + (size_t)((t + 1) & 1) * 3072 + tid * 6;
        *(float2*)(xs) = make_float2(p0.x, p0.y);
        *(float2*)(xs + 2) = make_float2(p0.z, p0.w);
        *(float2*)(xs + 4) = make_float2(p1.x, p1.y);
      }
      __syncthreads();  // B
      if (tid < 96) {
        __builtin_amdgcn_s_setprio(1);
        float z[4];
#pragma unroll
        for (int g = 0; g < 4; ++g) {
          const int cc = g * 16 + gj;
          float s = 0.f;
#pragma unroll
          for (int p = 0; p < 8; ++p) s += zred[p * ZSTRIDE + cc * 8 + gb];
          z[g] = s + bsl[cc];
        }
        creg = sigm(z[1]) * creg + sigm(z[0]) * ftanh(z[2]);
        const float hval = sigm(z[3]) * ftanh(creg);
        stp(h2ring + (size_t)(t & 7) * 3072 + (u0 + gj) * 6 + gb, hval, (uint)(t + 1));
        __builtin_amdgcn_s_setprio(0);
      }
    }
  } else {
    // --------------- L3: x = h2[t] live (K=512), h3 (K=128) -----------------
    float* hl = smem;                     // 3072
    float* hl3 = smem + 3072;             // 768
    float* zred = smem + 3840;            // 4160
    float* bsl = smem + 8000;             // 64
    const int wg3 = wg - 32, u0 = wg3 * 16;
    const int gcol = ((c >> 4) * 128) + u0 + (c & 15);
    float wxh2[64], wh3[16];
#pragma unroll
    for (int kk = 0; kk < 64; ++kk) wxh2[kk] = Wi3[(size_t)(w * 64 + kk) * 512 + gcol];
#pragma unroll
    for (int kk = 0; kk < 16; ++kk) wh3[kk] = Wh3[(size_t)(w * 16 + kk) * 512 + gcol];
    if (tid < 64) bsl[tid] = b3[((tid >> 4) * 128) + u0 + (tid & 15)];
    float creg = 0.f;

    for (int t = 0; t < TT; ++t) {
      // poll h3[t-1]: wave w covers atoms [96w, 96w+96); lanes<48 take 2 each
      const int lane = tid & 63;
      if (lane < 48) {
        float h2v[2];
        poll2(h3ring + (size_t)((t + 7) & 7) * 768 + 96 * w + 2 * lane, (uint)t, h2v);
        hl3[96 * w + 2 * lane] = h2v[0];
        hl3[96 * w + 2 * lane + 1] = h2v[1];
      }
      // poll h2[t] (stamp t+1) for unit tid
      {
        float hv[6];
        poll6(h2ring + (size_t)(t & 7) * 3072 + tid * 6, (uint)(t + 1), hv);
        float* hp = hl + tid * 6;
        *(float2*)(hp) = make_float2(hv[0], hv[1]);
        *(float2*)(hp + 2) = make_float2(hv[2], hv[3]);
        *(float2*)(hp + 4) = make_float2(hv[4], hv[5]);
      }
      lds_wave_fence();
      float acc[6] = {0, 0, 0, 0, 0, 0};
      {
        const float* hb = hl + (size_t)(w * 64) * 6;
#pragma unroll
        for (int kk = 0; kk < 64; ++kk) fma6(hb + kk * 6, wxh2[kk], acc);
        const float* h3b = hl3 + 96 * w;
#pragma unroll
        for (int kk = 0; kk < 16; ++kk) fma6(h3b + kk * 6, wh3[kk], acc);
      }
      {
        float* zr = zred + w * ZSTRIDE + c * 8;
        *(float4*)zr = make_float4(acc[0], acc[1], acc[2], acc[3]);
        *(float2*)(zr + 4) = make_float2(acc[4], acc[5]);
      }
      __syncthreads();  // B: all h2[t] reads done
      if (tid == 0) stf(flags3 + wg3, (uint)(t + 1));
      if (tid < 96) {
        __builtin_amdgcn_s_setprio(1);
        float z[4];
#pragma unroll
        for (int g = 0; g < 4; ++g) {
          const int cc = g * 16 + gj;
          float s = 0.f;
#pragma unroll
          for (int p = 0; p < 8; ++p) s += zred[p * ZSTRIDE + cc * 8 + gb];
          z[g] = s + bsl[cc];
        }
        creg = sigm(z[1]) * creg + sigm(z[0]) * ftanh(z[2]);
        const float hval = sigm(z[3]) * ftanh(creg);
        stp(h3ring + (size_t)(t & 7) * 768 + (u0 + gj) * 6 + gb, hval, (uint)(t + 1));
        if (t == TT - 1) h3fin[(u0 + gj) * 6 + gb] = hval;
        __builtin_amdgcn_s_setprio(0);
      }
      __syncthreads();  // C: protect zred (L3 polls L2's posts, not its own)
    }
  }
}

// ================= K3: out[b] = h3fin[:,b] @ Wl + bl ========================
__global__ void k_out(const float* __restrict__ h3fin, const float* __restrict__ Wl,
                      const float* __restrict__ bl, float* __restrict__ out) {
  const int tid = threadIdx.x;  // 64
  float p[NB] = {0, 0, 0, 0, 0, 0};
  for (int k = tid; k < 128; k += 64) {
    const float w = Wl[k];
#pragma unroll
    for (int b = 0; b < NB; ++b) p[b] += h3fin[k * 6 + b] * w;
  }
#pragma unroll
  for (int off = 32; off > 0; off >>= 1) {
#pragma unroll
    for (int b = 0; b < NB; ++b) p[b] += __shfl_down(p[b], off);
  }
  if (tid == 0) {
#pragma unroll
    for (int b = 0; b < NB; ++b) out[b] = p[b] + bl[0];
  }
}

// ================= host launcher ============================================
extern "C" void kernel_launch(void* const* d_in, const int* in_sizes, int n_in,
                              void* d_out, int out_size, void* d_ws, size_t ws_size,
                              hipStream_t stream) {
  (void)in_sizes; (void)n_in; (void)out_size;
  const float* x   = (const float*)d_in[0];
  const float* Wi1 = (const float*)d_in[1];
  const float* Wh1 = (const float*)d_in[2];
  const float* b1  = (const float*)d_in[3];
  const float* Wi2 = (const float*)d_in[4];
  const float* Wh2 = (const float*)d_in[5];
  const float* b2  = (const float*)d_in[6];
  const float* Wi3 = (const float*)d_in[7];
  const float* Wh3 = (const float*)d_in[8];
  const float* b3  = (const float*)d_in[9];
  const float* Wl  = (const float*)d_in[10];
  const float* bl  = (const float*)d_in[11];

  // ws layout (bytes):
  //   [0)       h1ring: 8*3072 u64 = 196608
  //   [196608)  h2ring: 8*3072 u64 = 196608
  //   [393216)  h3ring: 8*768  u64 =  49152
  //   [442368)  c1fin : 3072 f     =  12288
  //   [454656)  h3fin : 768 f      =   3072
  //   [457728)  flags3: 8 u32      (pad to 458752)
  //   [458752)  seq1  : 4096*512*8 f = 67108864  (padded [t][512][8])
  char* wsb = (char*)d_ws;
  u64*  h1ring = (u64*)(wsb + 0);
  u64*  h2ring = (u64*)(wsb + 196608);
  u64*  h3ring = (u64*)(wsb + 393216);
  float* c1fin = (float*)(wsb + 442368);
  float* h3fin = (float*)(wsb + 454656);
  uint* flags3 = (uint*)(wsb + 457728);
  float* seq1  = (float*)(wsb + 458752);

  const size_t need = 458752 + (size_t)TT * 512 * 8 * sizeof(float);
  if (ws_size < need) {
    hipMemsetAsync(d_out, 0, 6 * sizeof(float), stream);
    return;
  }

  // reset rings/stamps/flags/state every call (graph-replay safe).
  hipMemsetAsync(d_ws, 0, 458752, stream);

  k_l1<<<32, 512, 0, stream>>>(x, Wi1, Wh1, b1, h1ring, h2ring, c1fin, seq1);
  k_l23<<<40, 512, 0, stream>>>(seq1, Wi2, Wh2, b2, Wi3, Wh3, b3, c1fin,
                                h2ring, h3ring, h3fin, flags3);
  k_out<<<1, 64, 0, stream>>>(h3fin, Wl, bl, (float*)d_out);
}

// Round 5
// 158726.428 us; speedup vs baseline: 1.0327x; 1.0327x over previous
//
#include <hip/hip_runtime.h>

#define TT 4096
#define NB 6

typedef unsigned int uint;
typedef float f32x2 __attribute__((ext_vector_type(2)));

// ---------- raw sc0+sc1 transport (bypass L1+L2 both ways; PLAIN loads/stores,
// never atomic RMW). Values carry a 3-bit wrap tag in the mantissa LSBs. ------
__device__ __forceinline__ void st_sc(float* p, float v) {
  asm volatile("global_store_dword %0, %1, off sc0 sc1" :: "v"(p), "v"(v) : "memory");
}
__device__ __forceinline__ float tagf(float v, uint tg) {
  return __uint_as_float((__float_as_uint(v) & ~7u) | tg);
}

// poll 6 consecutive floats (one unit, b=0..5) until all carry tag tg.
__device__ __forceinline__ void poll6f(const float* p, uint tg, float out[6]) {
  for (;;) {
    f32x2 r0, r1, r2;
    asm volatile(
        "global_load_dwordx2 %0, %3, off sc0 sc1\n\t"
        "global_load_dwordx2 %1, %3, off offset:8 sc0 sc1\n\t"
        "global_load_dwordx2 %2, %3, off offset:16 sc0 sc1\n\t"
        "s_waitcnt vmcnt(0)"
        : "=&v"(r0), "=&v"(r1), "=&v"(r2)
        : "v"(p)
        : "memory");
    const uint b0 = __float_as_uint(r0[0]), b1 = __float_as_uint(r0[1]);
    const uint b2 = __float_as_uint(r1[0]), b3 = __float_as_uint(r1[1]);
    const uint b4 = __float_as_uint(r2[0]), b5 = __float_as_uint(r2[1]);
    if ((((b0 ^ tg) | (b1 ^ tg) | (b2 ^ tg) | (b3 ^ tg) | (b4 ^ tg) | (b5 ^ tg)) & 7u) == 0u) {
      out[0] = __uint_as_float(b0 & ~7u); out[1] = __uint_as_float(b1 & ~7u);
      out[2] = __uint_as_float(b2 & ~7u); out[3] = __uint_as_float(b3 & ~7u);
      out[4] = __uint_as_float(b4 & ~7u); out[5] = __uint_as_float(b5 & ~7u);
      return;
    }
    __builtin_amdgcn_s_sleep(1);
  }
}
__device__ __forceinline__ void poll2f(const float* p, uint tg, float out[2]) {
  for (;;) {
    f32x2 r0;
    asm volatile("global_load_dwordx2 %0, %1, off sc0 sc1\n\ts_waitcnt vmcnt(0)"
                 : "=&v"(r0) : "v"(p) : "memory");
    const uint b0 = __float_as_uint(r0[0]), b1 = __float_as_uint(r0[1]);
    if ((((b0 ^ tg) | (b1 ^ tg)) & 7u) == 0u) {
      out[0] = __uint_as_float(b0 & ~7u); out[1] = __uint_as_float(b1 & ~7u);
      return;
    }
    __builtin_amdgcn_s_sleep(1);
  }
}

// low-rate WAR flags (L2 vs L3 ring reuse) — atomics fine here (8 lanes, /4 steps)
__device__ __forceinline__ uint ldf(const uint* p) {
  return __hip_atomic_load(p, __ATOMIC_RELAXED, __HIP_MEMORY_SCOPE_AGENT);
}
__device__ __forceinline__ void stf(uint* p, uint v) {
  __hip_atomic_store(p, v, __ATOMIC_RELAXED, __HIP_MEMORY_SCOPE_AGENT);
}

__device__ __forceinline__ float sigm(float x) { return 1.f / (1.f + __expf(-x)); }
__device__ __forceinline__ float ftanh(float x) {
  x = fminf(fmaxf(x, -15.f), 15.f);
  const float e = __expf(-2.f * x);
  return (1.f - e) / (1.f + e);
}

// wave-local LDS fence: my wave's ds_writes complete before my ds_reads.
__device__ __forceinline__ void lds_wave_fence() {
  asm volatile("s_waitcnt lgkmcnt(0)" ::: "memory");
  __builtin_amdgcn_sched_barrier(0);
}

// acc[b] += v[k*6+b] * w  (LDS reads are wave-uniform => broadcast)
__device__ __forceinline__ void fma6(const float* vp, float w, float acc[6]) {
  const float2 v0 = *(const float2*)(vp);
  const float2 v1 = *(const float2*)(vp + 2);
  const float2 v2 = *(const float2*)(vp + 4);
  acc[0] += v0.x * w; acc[1] += v0.y * w; acc[2] += v1.x * w;
  acc[3] += v1.y * w; acc[4] += v2.x * w; acc[5] += v2.y * w;
}

#define ZS 520  // zred row stride (64 cols * 8 + 8 pad)

// ================= K1: LSTM layer 1 — 32 WGs x 512 thr, 16 units/WG =========
// col = tid&63 (4 gates x 16 units), wave w = tid>>6 owns h-k [64w,64w+64).
// Thread tid polls unit tid (6 floats). zred double-buffered by t&1 (WAR-safe
// with skew<=1); one __syncthreads per step.
__global__ __launch_bounds__(512) void k_l1(
    const float* __restrict__ x, const float* __restrict__ Wi,
    const float* __restrict__ Wh, const float* __restrict__ bias,
    float* h1ring, float* h2ring, float* c1fin, float* seq1) {
  __shared__ float xl[2][768];
  __shared__ float hl[3072];
  __shared__ float zred[2][8 * ZS];
  __shared__ float bs[64];
  const int tid = threadIdx.x, wg = blockIdx.x;
  const int c = tid & 63, w = tid >> 6;
  const int u0 = wg * 16;
  const int gcol = ((c >> 4) * 512) + u0 + (c & 15);
  float wh[64], wx[16];
#pragma unroll
  for (int kk = 0; kk < 64; ++kk) wh[kk] = Wh[(size_t)(w * 64 + kk) * 2048 + gcol];
#pragma unroll
  for (int kk = 0; kk < 16; ++kk) wx[kk] = Wi[(size_t)(w * 16 + kk) * 2048 + gcol];
  if (tid < 64) bs[tid] = bias[((tid >> 4) * 512) + u0 + (tid & 15)];
  const int gj = tid / 6, gb = tid % 6;  // gate lanes: tid<96
  float creg = 0.f;
  // prologue: stage x[0] into xl[0] (transpose [b][k] -> [k][6])
  {
    const float v0 = x[tid];
    float v1 = 0.f;
    if (tid < 256) v1 = x[512 + tid];
    xl[0][(tid & 127) * 6 + (tid >> 7)] = v0;
    if (tid < 256) { const int i = 512 + tid; xl[0][(i & 127) * 6 + (i >> 7)] = v1; }
  }
  __syncthreads();

  for (int t = 0; t < TT; ++t) {
    // prefetch x[t+1] into regs (consumed at stage; latency hidden)
    const float* xn = x + (size_t)((t + 1 < TT) ? t + 1 : TT - 1) * 768;
    const float v0p = xn[tid];
    float v1p = 0.f;
    if (tid < 256) v1p = xn[512 + tid];
    // x-part (overlaps the poll)
    float acc[6] = {0, 0, 0, 0, 0, 0};
    {
      const float* xb = xl[t & 1] + (size_t)(w * 16) * 6;
#pragma unroll
      for (int kk = 0; kk < 16; ++kk) fma6(xb + kk * 6, wx[kk], acc);
    }
    // poll h[t-1] for unit tid (slot (t-1)&7, tag ((t-1)>>3)&7)
    {
      float hv[6];
      poll6f(h1ring + (size_t)((t + 7) & 7) * 3072 + tid * 6,
             (uint)((t - 1) >> 3) & 7u, hv);
      float* hp = hl + tid * 6;
      *(float2*)(hp) = make_float2(hv[0], hv[1]);
      *(float2*)(hp + 2) = make_float2(hv[2], hv[3]);
      *(float2*)(hp + 4) = make_float2(hv[4], hv[5]);
    }
    lds_wave_fence();  // wave w wrote hl[64w..64w+64)*6 == slice it reads
    {
      const float* hb = hl + (size_t)(w * 64) * 6;
#pragma unroll
      for (int kk = 0; kk < 64; ++kk) fma6(hb + kk * 6, wh[kk], acc);
    }
    {
      float* zr = zred[t & 1] + w * ZS + c * 8;
      *(float4*)zr = make_float4(acc[0], acc[1], acc[2], acc[3]);
      *(float2*)(zr + 4) = make_float2(acc[4], acc[5]);
    }
    // stage xl[(t+1)&1]
    {
      float* xs = xl[(t + 1) & 1];
      xs[(tid & 127) * 6 + (tid >> 7)] = v0p;
      if (tid < 256) { const int i = 512 + tid; xs[(i & 127) * 6 + (i >> 7)] = v1p; }
    }
    __syncthreads();  // the only barrier per step
    if (tid < 96) {
      __builtin_amdgcn_s_setprio(1);
      const float* zb = zred[t & 1];
      float z[4];
#pragma unroll
      for (int g = 0; g < 4; ++g) {
        const int cc = g * 16 + gj;
        float s = 0.f;
#pragma unroll
        for (int p = 0; p < 8; ++p) s += zb[p * ZS + cc * 8 + gb];
        z[g] = s + bs[cc];
      }
      creg = sigm(z[1]) * creg + sigm(z[0]) * ftanh(z[2]);
      const float hval = sigm(z[3]) * ftanh(creg);
      const int gu = u0 + gj;
      st_sc(h1ring + (size_t)(t & 7) * 3072 + gu * 6 + gb,
            tagf(hval, (uint)(t >> 3) & 7u));
      __builtin_nontemporal_store(hval, seq1 + (size_t)t * 4096 + gu * 8 + gb);
      if (t == TT - 1) {
        st_sc(h2ring + (size_t)7 * 3072 + gu * 6 + gb, tagf(hval, 7u));  // L2 h-init
        c1fin[gu * 6 + gb] = creg;
      }
      __builtin_amdgcn_s_setprio(0);
    }
  }
}

// ===== K2: L2 (WGs 0..31, 16 units) + L3 (WGs 32..39, 16 units), skewed =====
__global__ __launch_bounds__(512) void k_l23(
    const float* __restrict__ seq1, const float* __restrict__ Wi2,
    const float* __restrict__ Wh2, const float* __restrict__ b2,
    const float* __restrict__ Wi3, const float* __restrict__ Wh3,
    const float* __restrict__ b3, const float* __restrict__ c1fin,
    float* h2ring, float* h3ring, float* h3fin, uint* flags3) {
  extern __shared__ float smem[];
  const int tid = threadIdx.x, wg = blockIdx.x;
  const int c = tid & 63, w = tid >> 6;
  const int gj = tid / 6, gb = tid % 6;

  if (wg < 32) {
    // --------------- L2: x = seq1[t] (K=512), h2 (K=512) --------------------
    float* xls = smem;            // 2 x 3072
    float* hl = smem + 6144;      // 3072
    float* zred = smem + 9216;    // 2 x 4160
    float* bsl = smem + 17536;    // 64
    const int u0 = wg * 16;
    const int gcol = ((c >> 4) * 512) + u0 + (c & 15);
    float wh[64], wx[64];
#pragma unroll
    for (int kk = 0; kk < 64; ++kk) {
      wh[kk] = Wh2[(size_t)(w * 64 + kk) * 2048 + gcol];
      wx[kk] = Wi2[(size_t)(w * 64 + kk) * 2048 + gcol];
    }
    if (tid < 64) bsl[tid] = b2[((tid >> 4) * 512) + u0 + (tid & 15)];
    float creg = (tid < 96) ? c1fin[(u0 + gj) * 6 + gb] : 0.f;
    // prologue: stage seq1[0] (thread tid = k-row tid; wave-self slice)
    {
      const float4 s0 = *(const float4*)(seq1 + (size_t)tid * 8);
      const float2 s1 = *(const float2*)(seq1 + (size_t)tid * 8 + 4);
      float* xs = xls + tid * 6;
      *(float2*)(xs) = make_float2(s0.x, s0.y);
      *(float2*)(xs + 2) = make_float2(s0.z, s0.w);
      *(float2*)(xs + 4) = make_float2(s1.x, s1.y);
    }
    __syncthreads();

    for (int t = 0; t < TT; ++t) {
      // WAR vs L3 (every 4 steps, tid<8; posts ordered after via barrier)
      if ((t & 3) == 0 && t >= 8 && tid < 8) {
        const uint need = (uint)(t - 4);
        while (ldf(flags3 + tid) < need) __builtin_amdgcn_s_sleep(1);
      }
      // prefetch seq1[t+1]
      const float* sn = seq1 + (size_t)((t + 1 < TT) ? t + 1 : TT - 1) * 4096;
      const float4 p0 = *(const float4*)(sn + (size_t)tid * 8);
      const float2 p1 = *(const float2*)(sn + (size_t)tid * 8 + 4);
      // x-part (overlaps the poll)
      float acc[6] = {0, 0, 0, 0, 0, 0};
      {
        const float* xb = xls + (size_t)(t & 1) * 3072 + (size_t)(w * 64) * 6;
#pragma unroll
        for (int kk = 0; kk < 64; ++kk) fma6(xb + kk * 6, wx[kk], acc);
      }
      // poll h2[t-1] for unit tid
      {
        float hv[6];
        poll6f(h2ring + (size_t)((t + 7) & 7) * 3072 + tid * 6,
               (uint)((t - 1) >> 3) & 7u, hv);
        float* hp = hl + tid * 6;
        *(float2*)(hp) = make_float2(hv[0], hv[1]);
        *(float2*)(hp + 2) = make_float2(hv[2], hv[3]);
        *(float2*)(hp + 4) = make_float2(hv[4], hv[5]);
      }
      lds_wave_fence();
      {
        const float* hb = hl + (size_t)(w * 64) * 6;
#pragma unroll
        for (int kk = 0; kk < 64; ++kk) fma6(hb + kk * 6, wh[kk], acc);
      }
      {
        float* zr = zred + (size_t)(t & 1) * 4160 + w * ZS + c * 8;
        *(float4*)zr = make_float4(acc[0], acc[1], acc[2], acc[3]);
        *(float2*)(zr + 4) = make_float2(acc[4], acc[5]);
      }
      // stage xls[(t+1)&1] (wave-self slice)
      {
        float* xs = xls + (size_t)((t + 1) & 1) * 3072 + tid * 6;
        *(float2*)(xs) = make_float2(p0.x, p0.y);
        *(float2*)(xs + 2) = make_float2(p0.z, p0.w);
        *(float2*)(xs + 4) = make_float2(p1.x, p1.y);
      }
      __syncthreads();
      if (tid < 96) {
        __builtin_amdgcn_s_setprio(1);
        const float* zb = zred + (size_t)(t & 1) * 4160;
        float z[4];
#pragma unroll
        for (int g = 0; g < 4; ++g) {
          const int cc = g * 16 + gj;
          float s = 0.f;
#pragma unroll
          for (int p = 0; p < 8; ++p) s += zb[p * ZS + cc * 8 + gb];
          z[g] = s + bsl[cc];
        }
        creg = sigm(z[1]) * creg + sigm(z[0]) * ftanh(z[2]);
        const float hval = sigm(z[3]) * ftanh(creg);
        st_sc(h2ring + (size_t)(t & 7) * 3072 + (u0 + gj) * 6 + gb,
              tagf(hval, (uint)(t >> 3) & 7u));
        __builtin_amdgcn_s_setprio(0);
      }
    }
  } else {
    // --------------- L3: x = h2[t] live (K=512), h3 (K=128) -----------------
    float* hl = smem;             // 3072
    float* hl3 = smem + 3072;     // 768
    float* zred = smem + 3840;    // 2 x 4160
    float* bsl = smem + 12160;    // 64
    const int wg3 = wg - 32, u0 = wg3 * 16;
    const int gcol = ((c >> 4) * 128) + u0 + (c & 15);
    float wxh2[64], wh3[16];
#pragma unroll
    for (int kk = 0; kk < 64; ++kk) wxh2[kk] = Wi3[(size_t)(w * 64 + kk) * 512 + gcol];
#pragma unroll
    for (int kk = 0; kk < 16; ++kk) wh3[kk] = Wh3[(size_t)(w * 16 + kk) * 512 + gcol];
    if (tid < 64) bsl[tid] = b3[((tid >> 4) * 128) + u0 + (tid & 15)];
    float creg = 0.f;

    for (int t = 0; t < TT; ++t) {
      const int lane = tid & 63;
      // poll h3[t-1]: wave w covers values [96w,96w+96); lanes<48 take 2 each
      if (lane < 48) {
        float h3v[2];
        poll2f(h3ring + (size_t)((t + 7) & 7) * 768 + 96 * w + 2 * lane,
               (uint)((t - 1) >> 3) & 7u, h3v);
        hl3[96 * w + 2 * lane] = h3v[0];
        hl3[96 * w + 2 * lane + 1] = h3v[1];
      }
      // poll h2[t] (slot t&7, tag (t>>3)&7) for unit tid
      {
        float hv[6];
        poll6f(h2ring + (size_t)(t & 7) * 3072 + tid * 6, (uint)(t >> 3) & 7u, hv);
        float* hp = hl + tid * 6;
        *(float2*)(hp) = make_float2(hv[0], hv[1]);
        *(float2*)(hp + 2) = make_float2(hv[2], hv[3]);
        *(float2*)(hp + 4) = make_float2(hv[4], hv[5]);
      }
      lds_wave_fence();
      float acc[6] = {0, 0, 0, 0, 0, 0};
      {
        const float* hb = hl + (size_t)(w * 64) * 6;
#pragma unroll
        for (int kk = 0; kk < 64; ++kk) fma6(hb + kk * 6, wxh2[kk], acc);
        const float* h3b = hl3 + 96 * w;
#pragma unroll
        for (int kk = 0; kk < 16; ++kk) fma6(h3b + kk * 6, wh3[kk], acc);
      }
      {
        float* zr = zred + (size_t)(t & 1) * 4160 + w * ZS + c * 8;
        *(float4*)zr = make_float4(acc[0], acc[1], acc[2], acc[3]);
        *(float2*)(zr + 4) = make_float2(acc[4], acc[5]);
      }
      __syncthreads();  // all h2[t] reads done
      if (tid == 0) stf(flags3 + wg3, (uint)(t + 1));
      if (tid < 96) {
        __builtin_amdgcn_s_setprio(1);
        const float* zb = zred + (size_t)(t & 1) * 4160;
        float z[4];
#pragma unroll
        for (int g = 0; g < 4; ++g) {
          const int cc = g * 16 + gj;
          float s = 0.f;
#pragma unroll
          for (int p = 0; p < 8; ++p) s += zb[p * ZS + cc * 8 + gb];
          z[g] = s + bsl[cc];
        }
        creg = sigm(z[1]) * creg + sigm(z[0]) * ftanh(z[2]);
        const float hval = sigm(z[3]) * ftanh(creg);
        st_sc(h3ring + (size_t)(t & 7) * 768 + (u0 + gj) * 6 + gb,
              tagf(hval, (uint)(t >> 3) & 7u));
        if (t == TT - 1) h3fin[(u0 + gj) * 6 + gb] = hval;
        __builtin_amdgcn_s_setprio(0);
      }
    }
  }
}

// ================= K3: out[b] = h3fin[:,b] @ Wl + bl ========================
__global__ void k_out(const float* __restrict__ h3fin, const float* __restrict__ Wl,
                      const float* __restrict__ bl, float* __restrict__ out) {
  const int tid = threadIdx.x;  // 64
  float p[NB] = {0, 0, 0, 0, 0, 0};
  for (int k = tid; k < 128; k += 64) {
    const float w = Wl[k];
#pragma unroll
    for (int b = 0; b < NB; ++b) p[b] += h3fin[k * 6 + b] * w;
  }
#pragma unroll
  for (int off = 32; off > 0; off >>= 1) {
#pragma unroll
    for (int b = 0; b < NB; ++b) p[b] += __shfl_down(p[b], off);
  }
  if (tid == 0) {
#pragma unroll
    for (int b = 0; b < NB; ++b) out[b] = p[b] + bl[0];
  }
}

// ================= host launcher ============================================
extern "C" void kernel_launch(void* const* d_in, const int* in_sizes, int n_in,
                              void* d_out, int out_size, void* d_ws, size_t ws_size,
                              hipStream_t stream) {
  (void)in_sizes; (void)n_in; (void)out_size;
  const float* x   = (const float*)d_in[0];
  const float* Wi1 = (const float*)d_in[1];
  const float* Wh1 = (const float*)d_in[2];
  const float* b1  = (const float*)d_in[3];
  const float* Wi2 = (const float*)d_in[4];
  const float* Wh2 = (const float*)d_in[5];
  const float* b2  = (const float*)d_in[6];
  const float* Wi3 = (const float*)d_in[7];
  const float* Wh3 = (const float*)d_in[8];
  const float* b3  = (const float*)d_in[9];
  const float* Wl  = (const float*)d_in[10];
  const float* bl  = (const float*)d_in[11];

  // ws layout (bytes):
  //   [0)       h1ring: 8*3072 f = 98304
  //   [98304)   h2ring: 8*3072 f = 98304
  //   [196608)  h3ring: 8*768  f = 24576
  //   [221184)  c1fin : 3072 f   = 12288
  //   [233472)  h3fin : 768 f    =  3072
  //   [236544)  flags3: 8 u32    (pad to 237568)
  //   [237568)  seq1  : 4096*512*8 f = 67108864  (padded [t][512][8])
  char* wsb = (char*)d_ws;
  float* h1ring = (float*)(wsb + 0);
  float* h2ring = (float*)(wsb + 98304);
  float* h3ring = (float*)(wsb + 196608);
  float* c1fin  = (float*)(wsb + 221184);
  float* h3fin  = (float*)(wsb + 233472);
  uint*  flags3 = (uint*)(wsb + 236544);
  float* seq1   = (float*)(wsb + 237568);

  const size_t need = 237568 + (size_t)TT * 512 * 8 * sizeof(float);
  if (ws_size < need) {
    hipMemsetAsync(d_out, 0, 6 * sizeof(float), stream);
    return;
  }

  // k_l23 needs 70.4 KB dynamic LDS
  hipFuncSetAttribute((const void*)k_l23, hipFuncAttributeMaxDynamicSharedMemorySize, 70400);

  // reset control region; seed t=-1 slots with tag 7 (byte 0x07 pattern:
  // tag bits = 7, value after tag-clear ~= 1e-34 ~ 0).
  hipMemsetAsync(d_ws, 0, 237568, stream);
  hipMemsetAsync(wsb + 7 * 3072 * 4, 0x07, 3072 * 4, stream);           // h1ring slot 7
  hipMemsetAsync(wsb + 196608 + 7 * 768 * 4, 0x07, 768 * 4, stream);    // h3ring slot 7

  k_l1<<<32, 512, 0, stream>>>(x, Wi1, Wh1, b1, h1ring, h2ring, c1fin, seq1);
  k_l23<<<40, 512, 70400, stream>>>(seq1, Wi2, Wh2, b2, Wi3, Wh3, b3, c1fin,
                                    h2ring, h3ring, h3fin, flags3);
  k_out<<<1, 64, 0, stream>>>(h3fin, Wl, bl, (float*)d_out);
}